// Round 6
// baseline (1009.115 us; speedup 1.0000x reference)
//
#include <hip/hip_runtime.h>

#define USER_NUM 100000
#define ITEM_NUM 100000
#define NN 200000
#define DIM 64
#define EPSV 0.2f

#define NBLK 782        // ceil(NN/256) blocks for node-indexed kernels
#define SRC_MASK 0x3FFFF

// ---------------------------------------------------------------------------
// H1: per-node edge histogram via global atomics (h is 800KB, L2-resident;
// ~16 edges/node uniform random -> negligible same-address serialization)
// ---------------------------------------------------------------------------
__global__ __launch_bounds__(256) void hist_k(const int* __restrict__ dst,
                                              int* __restrict__ h, int E) {
    int e = blockIdx.x * 256 + threadIdx.x;
    if (e < E) atomicAdd(&h[dst[e]], 1);
}

// ---------------------------------------------------------------------------
// S1: per-block (256-node) partial sums of the histogram
// ---------------------------------------------------------------------------
__global__ __launch_bounds__(256) void psum_k(const int* __restrict__ h,
                                              int* __restrict__ bsum) {
    __shared__ int tmp[256];
    int b = blockIdx.x, t = threadIdx.x;
    int i = b * 256 + t;
    tmp[t] = (i < NN) ? h[i] : 0;
    __syncthreads();
    for (int o = 128; o > 0; o >>= 1) {
        if (t < o) tmp[t] += tmp[t + o];
        __syncthreads();
    }
    if (t == 0) bsum[b] = tmp[0];
}

// ---------------------------------------------------------------------------
// S2: exclusive scan of the 782 block sums (single block, 4 per thread),
// in-place; also seeds row_ptr[NN] = E.
// ---------------------------------------------------------------------------
__global__ __launch_bounds__(256) void bscan2_k(int* __restrict__ bsum,
                                                int* __restrict__ row_ptr, int E) {
    __shared__ int tmp[256];
    int t = threadIdx.x;
    int i0 = 4 * t;
    int v0 = (i0     < NBLK) ? bsum[i0]     : 0;
    int v1 = (i0 + 1 < NBLK) ? bsum[i0 + 1] : 0;
    int v2 = (i0 + 2 < NBLK) ? bsum[i0 + 2] : 0;
    int v3 = (i0 + 3 < NBLK) ? bsum[i0 + 3] : 0;
    int s = v0 + v1 + v2 + v3;
    tmp[t] = s;
    __syncthreads();
    for (int o = 1; o < 256; o <<= 1) {
        int x = (t >= o) ? tmp[t - o] : 0;
        __syncthreads();
        tmp[t] += x;
        __syncthreads();
    }
    int excl = tmp[t] - s;
    if (i0     < NBLK) bsum[i0]     = excl;
    if (i0 + 1 < NBLK) bsum[i0 + 1] = excl + v0;
    if (i0 + 2 < NBLK) bsum[i0 + 2] = excl + v0 + v1;
    if (i0 + 3 < NBLK) bsum[i0 + 3] = excl + v0 + v1 + v2;
    if (t == 0) row_ptr[NN] = E;
}

// ---------------------------------------------------------------------------
// S3: intra-block exclusive scan + block base -> row_ptr and cursor copy
// ---------------------------------------------------------------------------
__global__ __launch_bounds__(256) void rowptr_k(const int* __restrict__ h,
                                                const int* __restrict__ bsum,
                                                int* __restrict__ row_ptr,
                                                int* __restrict__ cursor) {
    __shared__ int tmp[256];
    int b = blockIdx.x, t = threadIdx.x;
    int i = b * 256 + t;
    int v = (i < NN) ? h[i] : 0;
    tmp[t] = v;
    __syncthreads();
    for (int o = 1; o < 256; o <<= 1) {
        int x = (t >= o) ? tmp[t - o] : 0;
        __syncthreads();
        tmp[t] += x;
        __syncthreads();
    }
    if (i < NN) {
        int p = bsum[b] + tmp[t] - v;
        row_ptr[i] = p;
        cursor[i] = p;
    }
}

// ---------------------------------------------------------------------------
// S4: scatter edges to CSR position via atomic row cursors. Within-row order
// is nondeterministic across replays -- tolerated by the f64 accumulation in
// spmm (round-1 lesson). ssv window is 25.6MB (L2/L3-resident).
// ---------------------------------------------------------------------------
__global__ __launch_bounds__(256) void scat_k(const int* __restrict__ src,
                                              const int* __restrict__ dst,
                                              const float* __restrict__ vals,
                                              int* __restrict__ cursor,
                                              int2* __restrict__ ssv, int E) {
    int e = blockIdx.x * 256 + threadIdx.x;
    if (e < E) {
        int d = dst[e];
        int pos = atomicAdd(&cursor[d], 1);
        ssv[pos] = make_int2(src[e], __float_as_int(vals[e]));
    }
}

// RNE f32 -> bf16 pack (two floats -> one uint, low half = first)
__device__ __forceinline__ unsigned int bpack(float a, float b) {
    unsigned int ua = __float_as_uint(a), ub = __float_as_uint(b);
    ua = (ua + 0x7fffu + ((ua >> 16) & 1u)) >> 16;
    ub = (ub + 0x7fffu + ((ub >> 16) & 1u)) >> 16;
    return ua | (ub << 16);
}

__device__ __forceinline__ float bsign(float x) {
    return (x > 0.f) ? 1.f : ((x < 0.f) ? -1.f : 0.f);
}

// ---------------------------------------------------------------------------
// K0: convert concat(user_emb, item_emb) f32 -> bf16 table [NN][64]
// (must run AFTER scat_k: its output aliases the hist/cursor scratch)
// ---------------------------------------------------------------------------
__global__ __launch_bounds__(256) void cvt_k(const float* __restrict__ ue,
                                             const float* __restrict__ ie,
                                             unsigned int* __restrict__ out) {
    long long i = (long long)blockIdx.x * 256 + threadIdx.x;   // float4 index
    const long long tot = (long long)NN * (DIM / 4);           // 3.2M
    if (i >= tot) return;
    const long long uu = (long long)USER_NUM * (DIM / 4);
    const float4 v = (i < uu) ? reinterpret_cast<const float4*>(ue)[i]
                              : reinterpret_cast<const float4*>(ie)[i - uu];
    uint2 p; p.x = bpack(v.x, v.y); p.y = bpack(v.z, v.w);
    reinterpret_cast<uint2*>(out)[i] = p;
}

// unpack a uint4 (8 bf16) and fma into the 8 f64 accumulators
#define FMA8(q, vv)                                                          \
    do {                                                                     \
        float t0 = __uint_as_float((q).x << 16);                             \
        float t1 = __uint_as_float((q).x & 0xffff0000u);                     \
        float t2 = __uint_as_float((q).y << 16);                             \
        float t3 = __uint_as_float((q).y & 0xffff0000u);                     \
        float t4 = __uint_as_float((q).z << 16);                             \
        float t5 = __uint_as_float((q).z & 0xffff0000u);                     \
        float t6 = __uint_as_float((q).w << 16);                             \
        float t7 = __uint_as_float((q).w & 0xffff0000u);                     \
        a0 = fma((double)t0, (vv), a0); a1 = fma((double)t1, (vv), a1);      \
        a2 = fma((double)t2, (vv), a2); a3 = fma((double)t3, (vv), a3);      \
        a4 = fma((double)t4, (vv), a4); a5 = fma((double)t5, (vv), a5);      \
        a6 = fma((double)t6, (vv), a6); a7 = fma((double)t7, (vv), a7);      \
    } while (0)

// ---------------------------------------------------------------------------
// fused segmented SpMM + noise injection + acc (unchanged from round 5).
// one 64-lane wave per dst row; 8 edge-groups x 8 lanes; lane gathers
// uint4 = 8 bf16 dims. f64 accumulation for replay-stability.
// ---------------------------------------------------------------------------
__global__ __launch_bounds__(256) void spmm_fused_k(const int* __restrict__ row_ptr,
                                                    const int2* __restrict__ ssv,
                                                    const unsigned int* __restrict__ ego,
                                                    unsigned int* __restrict__ ego_out,
                                                    float* __restrict__ cl_out,
                                                    const float* __restrict__ nz_layer,
                                                    float* __restrict__ acc,
                                                    int is_first, int is_last) {
    int node = blockIdx.x * 4 + (threadIdx.x >> 6);
    int lane = threadIdx.x & 63;
    int g    = lane >> 3;           // edge slot 0..7 within an 8-edge block
    int d8   = lane & 7;            // which 8-dim chunk of the 64 dims
    int beg = row_ptr[node];
    int end = row_ptr[node + 1];

    double a0 = 0, a1 = 0, a2 = 0, a3 = 0, a4 = 0, a5 = 0, a6 = 0, a7 = 0;
    int base = beg;

    for (; base + 16 <= end; base += 16) {
        int2 svA = ssv[base + g];
        int2 svB = ssv[base + 8 + g];
        int sA = svA.x & SRC_MASK;
        int sB = svB.x & SRC_MASK;
        const uint4 qA = *reinterpret_cast<const uint4*>(ego + ((size_t)sA << 5) + (d8 << 2));
        const uint4 qB = *reinterpret_cast<const uint4*>(ego + ((size_t)sB << 5) + (d8 << 2));
        double vA = (double)__int_as_float(svA.y);
        double vB = (double)__int_as_float(svB.y);
        FMA8(qA, vA);
        FMA8(qB, vB);
    }
    if (base + 8 <= end) {
        int2 sv = ssv[base + g];
        int s = sv.x & SRC_MASK;
        const uint4 q = *reinterpret_cast<const uint4*>(ego + ((size_t)s << 5) + (d8 << 2));
        double v = (double)__int_as_float(sv.y);
        FMA8(q, v);
        base += 8;
    }
    int rem = end - base;
    if (rem > 0) {
        int2 sv = ssv[base + ((g < rem) ? g : 0)];
        int s = sv.x & SRC_MASK;
        const uint4 q = *reinterpret_cast<const uint4*>(ego + ((size_t)s << 5) + (d8 << 2));
        double v = (g < rem) ? (double)__int_as_float(sv.y) : 0.0;
        FMA8(q, v);
    }

    // reduce the 8 edge groups (lane bits 3,4,5), fixed deterministic order
    a0 += __shfl_xor(a0, 8, 64);  a1 += __shfl_xor(a1, 8, 64);
    a2 += __shfl_xor(a2, 8, 64);  a3 += __shfl_xor(a3, 8, 64);
    a4 += __shfl_xor(a4, 8, 64);  a5 += __shfl_xor(a5, 8, 64);
    a6 += __shfl_xor(a6, 8, 64);  a7 += __shfl_xor(a7, 8, 64);
    a0 += __shfl_xor(a0, 16, 64); a1 += __shfl_xor(a1, 16, 64);
    a2 += __shfl_xor(a2, 16, 64); a3 += __shfl_xor(a3, 16, 64);
    a4 += __shfl_xor(a4, 16, 64); a5 += __shfl_xor(a5, 16, 64);
    a6 += __shfl_xor(a6, 16, 64); a7 += __shfl_xor(a7, 16, 64);
    a0 += __shfl_xor(a0, 32, 64); a1 += __shfl_xor(a1, 32, 64);
    a2 += __shfl_xor(a2, 32, 64); a3 += __shfl_xor(a3, 32, 64);
    a4 += __shfl_xor(a4, 32, 64); a5 += __shfl_xor(a5, 32, 64);
    a6 += __shfl_xor(a6, 32, 64); a7 += __shfl_xor(a7, 32, 64);

    float f0 = (float)a0, f1 = (float)a1, f2 = (float)a2, f3 = (float)a3;
    float f4 = (float)a4, f5 = (float)a5, f6 = (float)a6, f7 = (float)a7;

    size_t off = (size_t)node * DIM + (d8 << 3);
    const float4 n0 = *reinterpret_cast<const float4*>(nz_layer + off);
    const float4 n1 = *reinterpret_cast<const float4*>(nz_layer + off + 4);
    float ss = n0.x * n0.x + n0.y * n0.y + n0.z * n0.z + n0.w * n0.w
             + n1.x * n1.x + n1.y * n1.y + n1.z * n1.z + n1.w * n1.w;
    // reduce over the 8 dim-chunk lanes (edge groups hold identical copies)
    ss += __shfl_xor(ss, 1, 64);
    ss += __shfl_xor(ss, 2, 64);
    ss += __shfl_xor(ss, 4, 64);
    float e = EPSV / fmaxf(sqrtf(ss), 1e-12f);

    float w0 = f0 + bsign(f0) * n0.x * e;
    float w1 = f1 + bsign(f1) * n0.y * e;
    float w2 = f2 + bsign(f2) * n0.z * e;
    float w3 = f3 + bsign(f3) * n0.w * e;
    float w4 = f4 + bsign(f4) * n1.x * e;
    float w5 = f5 + bsign(f5) * n1.y * e;
    float w6 = f6 + bsign(f6) * n1.z * e;
    float w7 = f7 + bsign(f7) * n1.w * e;

    if (g == 0) {
        if (!is_last) {
            uint4 p;
            p.x = bpack(w0, w1); p.y = bpack(w2, w3);
            p.z = bpack(w4, w5); p.w = bpack(w6, w7);
            *reinterpret_cast<uint4*>(ego_out + ((size_t)node << 5) + (d8 << 2)) = p;
        }
        float4 v0 = make_float4(w0, w1, w2, w3);
        float4 v1 = make_float4(w4, w5, w6, w7);
        if (cl_out) {
            *reinterpret_cast<float4*>(cl_out + off)     = v0;
            *reinterpret_cast<float4*>(cl_out + off + 4) = v1;
        }
        float4 r0, r1;
        if (is_first) {
            r0 = v0; r1 = v1;
        } else {
            const float4 p0 = *reinterpret_cast<const float4*>(acc + off);
            const float4 p1 = *reinterpret_cast<const float4*>(acc + off + 4);
            r0.x = p0.x + v0.x; r0.y = p0.y + v0.y; r0.z = p0.z + v0.z; r0.w = p0.w + v0.w;
            r1.x = p1.x + v1.x; r1.y = p1.y + v1.y; r1.z = p1.z + v1.z; r1.w = p1.w + v1.w;
        }
        if (is_last) {
            const float k = 1.0f / 3.0f;
            r0.x *= k; r0.y *= k; r0.z *= k; r0.w *= k;
            r1.x *= k; r1.y *= k; r1.z *= k; r1.w *= k;
        }
        *reinterpret_cast<float4*>(acc + off)     = r0;
        *reinterpret_cast<float4*>(acc + off + 4) = r1;
    }
}

extern "C" void kernel_launch(void* const* d_in, const int* in_sizes, int n_in,
                              void* d_out, int out_size, void* d_ws, size_t ws_size,
                              hipStream_t stream) {
    const float* user_emb = (const float*)d_in[0];
    const float* item_emb = (const float*)d_in[1];
    const int*   adj_src  = (const int*)d_in[2];
    const int*   adj_dst  = (const int*)d_in[3];
    const float* adj_vals = (const float*)d_in[4];
    const float* noise    = (const float*)d_in[5];
    const int E = in_sizes[2];

    const long long ND = (long long)NN * DIM;
    float* out_final = (float*)d_out;       // [NN, D] final
    float* out_cl    = out_final + ND;      // [NN, D] cl

    // workspace layout (~77.7 MB):
    //  [0, 25.6MB)      egoB0 (bf16 table). During preprocessing this region
    //                   hosts h (hist, 800KB @ +0) and cursor (800KB @ +1MB);
    //                   cvt_k overwrites them AFTER scat_k.
    //  [25.6, 51.2MB)   egoB1 (bf16 ego, layer-1 output)
    //  [51.2, 76.8MB)   ssv (CSR records)
    //  [76.8MB, ...)    row_ptr (NN+1), bsum (NBLK)
    char* w = (char*)d_ws;
    const long long B16 = (long long)NN * (DIM / 2) * 4;   // 25.6 MB
    unsigned int* egoB0 = (unsigned int*)w;
    int*          h      = (int*)w;                          // alias, dead b4 cvt
    int*          cursor = (int*)(w + (1 << 20));            // alias, dead b4 cvt
    unsigned int* egoB1 = (unsigned int*)(w + B16);
    int2*         ssv   = (int2*)(w + 2 * B16);
    int*   row_ptr = (int*)(w + 3 * B16);                    // NN + 1
    int*   bsum    = row_ptr + NN + 1;                       // NBLK

    const int egrid = (E + 255) / 256;

    hipMemsetAsync(h, 0, NN * sizeof(int), stream);
    hist_k<<<egrid, 256, 0, stream>>>(adj_dst, h, E);
    psum_k<<<NBLK, 256, 0, stream>>>(h, bsum);
    bscan2_k<<<1, 256, 0, stream>>>(bsum, row_ptr, E);
    rowptr_k<<<NBLK, 256, 0, stream>>>(h, bsum, row_ptr, cursor);
    scat_k<<<egrid, 256, 0, stream>>>(adj_src, adj_dst, adj_vals, cursor, ssv, E);
    // h / cursor dead -> egoB0 safe to write
    cvt_k<<<(int)(((long long)NN * (DIM / 4) + 255) / 256), 256, 0, stream>>>(
        user_emb, item_emb, egoB0);

    const int spmm_grid = NN / 4;   // 200000 waves, one per dst row
    // layer 1: gather egoB0 -> ego egoB1 (bf16) + cl (f32) ; acc = val
    spmm_fused_k<<<spmm_grid, 256, 0, stream>>>(row_ptr, ssv, egoB0, egoB1,
                                                out_cl, noise, out_final, 1, 0);
    // layer 2: gather egoB1 -> egoB0 (bf16) ; acc += val
    spmm_fused_k<<<spmm_grid, 256, 0, stream>>>(row_ptr, ssv, egoB1, egoB0,
                                                nullptr, noise + ND, out_final, 0, 0);
    // layer 3: gather egoB0 -> (none) ; acc = (acc + val)/3
    spmm_fused_k<<<spmm_grid, 256, 0, stream>>>(row_ptr, ssv, egoB0, nullptr,
                                                nullptr, noise + 2 * ND, out_final, 0, 1);
}

// Round 7
// 773.845 us; speedup vs baseline: 1.3040x; 1.3040x over previous
//
#include <hip/hip_runtime.h>

#define USER_NUM 100000
#define ITEM_NUM 100000
#define NN 200000
#define DIM 64
#define EPSV 0.2f

#define NB 782          // buckets of 256 dst-nodes (ceil(200000/256))
#define BSH 8           // bucket = dst >> 8
#define NPB 256         // nodes per bucket
#define CH 4096         // edges per workgroup chunk in pass A
#define PER 16          // edges per thread (256*16 = 4096)
#define SRC_MASK 0x3FFFF

// ---------------------------------------------------------------------------
// K1: coarse bucket histogram (782 counters) via LDS aggregation
// ---------------------------------------------------------------------------
__global__ __launch_bounds__(256) void bhist_k(const int* __restrict__ dst,
                                               int* __restrict__ bhist, int E) {
    __shared__ int h[NB];
    int t = threadIdx.x;
    for (int i = t; i < NB; i += 256) h[i] = 0;
    __syncthreads();
    long long base = (long long)blockIdx.x * CH;
    #pragma unroll
    for (int j = 0; j < PER; ++j) {
        long long e = base + t + j * 256;
        if (e < E) atomicAdd(&h[dst[e] >> BSH], 1);
    }
    __syncthreads();
    for (int i = t; i < NB; i += 256) if (h[i]) atomicAdd(&bhist[i], h[i]);
}

// ---------------------------------------------------------------------------
// K2: exclusive scan over 782 bucket counts (single block, 4 per thread)
// ---------------------------------------------------------------------------
__global__ __launch_bounds__(256) void bscan_k(const int* __restrict__ bhist,
                                               int* __restrict__ bucket_base,
                                               int* __restrict__ bucket_off,
                                               int* __restrict__ row_ptr, int E) {
    __shared__ int tmp[256];
    int t = threadIdx.x;
    int i0 = 4 * t;
    int v0 = (i0     < NB) ? bhist[i0]     : 0;
    int v1 = (i0 + 1 < NB) ? bhist[i0 + 1] : 0;
    int v2 = (i0 + 2 < NB) ? bhist[i0 + 2] : 0;
    int v3 = (i0 + 3 < NB) ? bhist[i0 + 3] : 0;
    int s = v0 + v1 + v2 + v3;
    tmp[t] = s;
    __syncthreads();
    for (int o = 1; o < 256; o <<= 1) {
        int x = (t >= o) ? tmp[t - o] : 0;
        __syncthreads();
        tmp[t] += x;
        __syncthreads();
    }
    int excl = tmp[t] - s;
    int e0 = excl, e1 = excl + v0, e2 = e1 + v1, e3 = e2 + v2;
    if (i0     < NB) { bucket_base[i0]     = e0; bucket_off[i0]     = e0; }
    if (i0 + 1 < NB) { bucket_base[i0 + 1] = e1; bucket_off[i0 + 1] = e1; }
    if (i0 + 2 < NB) { bucket_base[i0 + 2] = e2; bucket_off[i0 + 2] = e2; }
    if (i0 + 3 < NB) { bucket_base[i0 + 3] = e3; bucket_off[i0 + 3] = e3; }
    if (t == 0) { bucket_base[NB] = E; row_ptr[NN] = E; }
}

// ---------------------------------------------------------------------------
// K3 (pass A): LDS multi-split into 782 bucket regions, dense run writes.
// Record: x = src | (dst&255)<<18 ; y = val bits.
// ---------------------------------------------------------------------------
__global__ __launch_bounds__(256) void apart_k(const int* __restrict__ src,
                                               const int* __restrict__ dst,
                                               const float* __restrict__ vals,
                                               int* __restrict__ bucket_off,
                                               int2* __restrict__ out, int E) {
    __shared__ int cnt[NB], start[NB], cursor[NB], gbase[NB];   // 12.5 KB
    __shared__ int tmp[256];
    __shared__ int2 rec[CH];                                    // 32 KB
    int t = threadIdx.x;
    long long base = (long long)blockIdx.x * CH;
    int nvalid = (int)min((long long)CH, (long long)E - base);

    int s_[PER]; int d_[PER]; float v_[PER];
    for (int i = t; i < NB; i += 256) cnt[i] = 0;
    __syncthreads();
    #pragma unroll
    for (int j = 0; j < PER; ++j) {
        int idx = t + j * 256;
        if (idx < nvalid) {
            long long e = base + idx;
            d_[j] = dst[e]; s_[j] = src[e]; v_[j] = vals[e];
            atomicAdd(&cnt[d_[j] >> BSH], 1);
        } else d_[j] = -1;
    }
    __syncthreads();
    // exclusive scan of 782 counters, 4 per thread
    int i0 = 4 * t;
    int c0 = (i0     < NB) ? cnt[i0]     : 0;
    int c1 = (i0 + 1 < NB) ? cnt[i0 + 1] : 0;
    int c2 = (i0 + 2 < NB) ? cnt[i0 + 2] : 0;
    int c3 = (i0 + 3 < NB) ? cnt[i0 + 3] : 0;
    int s = c0 + c1 + c2 + c3;
    tmp[t] = s;
    __syncthreads();
    for (int o = 1; o < 256; o <<= 1) {
        int x = (t >= o) ? tmp[t - o] : 0;
        __syncthreads();
        tmp[t] += x;
        __syncthreads();
    }
    int excl = tmp[t] - s;
    int p0 = excl, p1 = excl + c0, p2 = p1 + c1, p3 = p2 + c2;
    if (i0     < NB) { start[i0]     = p0; cursor[i0]     = p0; }
    if (i0 + 1 < NB) { start[i0 + 1] = p1; cursor[i0 + 1] = p1; }
    if (i0 + 2 < NB) { start[i0 + 2] = p2; cursor[i0 + 2] = p2; }
    if (i0 + 3 < NB) { start[i0 + 3] = p3; cursor[i0 + 3] = p3; }
    __syncthreads();
    for (int i = t; i < NB; i += 256) {
        int c = cnt[i];
        gbase[i] = (c > 0) ? atomicAdd(&bucket_off[i], c) : 0;
    }
    __syncthreads();
    #pragma unroll
    for (int j = 0; j < PER; ++j) {
        if (d_[j] >= 0) {
            int b = d_[j] >> BSH;
            int slot = atomicAdd(&cursor[b], 1);
            rec[slot] = make_int2(s_[j] | ((d_[j] & (NPB - 1)) << 18),
                                  __float_as_int(v_[j]));
        }
    }
    __syncthreads();
    // flush: consecutive LDS slots -> contiguous global runs per bucket
    for (int slot = t; slot < nvalid; slot += 256) {
        int lo = 0, hi = NB - 1;
        while (lo < hi) {
            int mid = (lo + hi + 1) >> 1;
            if (start[mid] <= slot) lo = mid; else hi = mid - 1;
        }
        out[gbase[lo] + (slot - start[lo])] = rec[slot];
    }
}

// ---------------------------------------------------------------------------
// K4 (pass B): one WG per 256-node bucket (782 blocks, ~3/CU). Per-node hist
// + single 256-scan in LDS -> row_ptr, then scatter to final CSR position
// (random only within a ~32KB L2-hot window).
// ---------------------------------------------------------------------------
__global__ __launch_bounds__(256) void bsort_k(const int* __restrict__ bucket_base,
                                               const int2* __restrict__ in,
                                               int2* __restrict__ out,
                                               int* __restrict__ row_ptr) {
    __shared__ int noff[NPB];
    __shared__ int tmp[256];
    int b = blockIdx.x, t = threadIdx.x;
    int rbeg = bucket_base[b], rend = bucket_base[b + 1];
    noff[t] = 0;
    __syncthreads();
    for (int i = rbeg + t; i < rend; i += 256)
        atomicAdd(&noff[(in[i].x >> 18) & (NPB - 1)], 1);
    __syncthreads();
    int v = noff[t];
    tmp[t] = v;
    __syncthreads();
    for (int o = 1; o < 256; o <<= 1) {
        int x = (t >= o) ? tmp[t - o] : 0;
        __syncthreads();
        tmp[t] += x;
        __syncthreads();
    }
    int e0 = rbeg + tmp[t] - v;
    int node0 = b * NPB + t;
    if (node0 < NN) row_ptr[node0] = e0;
    noff[t] = e0;
    __syncthreads();
    for (int i = rbeg + t; i < rend; i += 256) {
        int2 r = in[i];
        int pos = atomicAdd(&noff[(r.x >> 18) & (NPB - 1)], 1);
        out[pos] = r;
    }
}

// RNE f32 -> bf16 pack (two floats -> one uint, low half = first)
__device__ __forceinline__ unsigned int bpack(float a, float b) {
    unsigned int ua = __float_as_uint(a), ub = __float_as_uint(b);
    ua = (ua + 0x7fffu + ((ua >> 16) & 1u)) >> 16;
    ub = (ub + 0x7fffu + ((ub >> 16) & 1u)) >> 16;
    return ua | (ub << 16);
}

__device__ __forceinline__ float bsign(float x) {
    return (x > 0.f) ? 1.f : ((x < 0.f) ? -1.f : 0.f);
}

// ---------------------------------------------------------------------------
// K0: convert concat(user_emb, item_emb) f32 -> bf16 table [NN][64]
// (runs after bsort_k; its output aliases the dead pass-A buffer)
// ---------------------------------------------------------------------------
__global__ __launch_bounds__(256) void cvt_k(const float* __restrict__ ue,
                                             const float* __restrict__ ie,
                                             unsigned int* __restrict__ out) {
    long long i = (long long)blockIdx.x * 256 + threadIdx.x;   // float4 index
    const long long tot = (long long)NN * (DIM / 4);           // 3.2M
    if (i >= tot) return;
    const long long uu = (long long)USER_NUM * (DIM / 4);
    const float4 v = (i < uu) ? reinterpret_cast<const float4*>(ue)[i]
                              : reinterpret_cast<const float4*>(ie)[i - uu];
    uint2 p; p.x = bpack(v.x, v.y); p.y = bpack(v.z, v.w);
    reinterpret_cast<uint2*>(out)[i] = p;
}

// unpack a uint4 (8 bf16) and fma into the 8 f64 accumulators
#define FMA8(q, vv)                                                          \
    do {                                                                     \
        float t0 = __uint_as_float((q).x << 16);                             \
        float t1 = __uint_as_float((q).x & 0xffff0000u);                     \
        float t2 = __uint_as_float((q).y << 16);                             \
        float t3 = __uint_as_float((q).y & 0xffff0000u);                     \
        float t4 = __uint_as_float((q).z << 16);                             \
        float t5 = __uint_as_float((q).z & 0xffff0000u);                     \
        float t6 = __uint_as_float((q).w << 16);                             \
        float t7 = __uint_as_float((q).w & 0xffff0000u);                     \
        a0 = fma((double)t0, (vv), a0); a1 = fma((double)t1, (vv), a1);      \
        a2 = fma((double)t2, (vv), a2); a3 = fma((double)t3, (vv), a3);      \
        a4 = fma((double)t4, (vv), a4); a5 = fma((double)t5, (vv), a5);      \
        a6 = fma((double)t6, (vv), a6); a7 = fma((double)t7, (vv), a7);      \
    } while (0)

// ---------------------------------------------------------------------------
// fused segmented SpMM + noise injection + acc (unchanged from round 5).
// one 64-lane wave per dst row; 8 edge-groups x 8 lanes; lane gathers
// uint4 = 8 bf16 dims. f64 accumulation for replay-stability (CSR edge order
// varies across graph replays; sign() is discontinuous -- round-1 failure).
// ---------------------------------------------------------------------------
__global__ __launch_bounds__(256) void spmm_fused_k(const int* __restrict__ row_ptr,
                                                    const int2* __restrict__ ssv,
                                                    const unsigned int* __restrict__ ego,
                                                    unsigned int* __restrict__ ego_out,
                                                    float* __restrict__ cl_out,
                                                    const float* __restrict__ nz_layer,
                                                    float* __restrict__ acc,
                                                    int is_first, int is_last) {
    int node = blockIdx.x * 4 + (threadIdx.x >> 6);
    int lane = threadIdx.x & 63;
    int g    = lane >> 3;           // edge slot 0..7 within an 8-edge block
    int d8   = lane & 7;            // which 8-dim chunk of the 64 dims
    int beg = row_ptr[node];
    int end = row_ptr[node + 1];

    double a0 = 0, a1 = 0, a2 = 0, a3 = 0, a4 = 0, a5 = 0, a6 = 0, a7 = 0;
    int base = beg;

    for (; base + 16 <= end; base += 16) {
        int2 svA = ssv[base + g];
        int2 svB = ssv[base + 8 + g];
        int sA = svA.x & SRC_MASK;
        int sB = svB.x & SRC_MASK;
        const uint4 qA = *reinterpret_cast<const uint4*>(ego + ((size_t)sA << 5) + (d8 << 2));
        const uint4 qB = *reinterpret_cast<const uint4*>(ego + ((size_t)sB << 5) + (d8 << 2));
        double vA = (double)__int_as_float(svA.y);
        double vB = (double)__int_as_float(svB.y);
        FMA8(qA, vA);
        FMA8(qB, vB);
    }
    if (base + 8 <= end) {
        int2 sv = ssv[base + g];
        int s = sv.x & SRC_MASK;
        const uint4 q = *reinterpret_cast<const uint4*>(ego + ((size_t)s << 5) + (d8 << 2));
        double v = (double)__int_as_float(sv.y);
        FMA8(q, v);
        base += 8;
    }
    int rem = end - base;
    if (rem > 0) {
        int2 sv = ssv[base + ((g < rem) ? g : 0)];
        int s = sv.x & SRC_MASK;
        const uint4 q = *reinterpret_cast<const uint4*>(ego + ((size_t)s << 5) + (d8 << 2));
        double v = (g < rem) ? (double)__int_as_float(sv.y) : 0.0;
        FMA8(q, v);
    }

    // reduce the 8 edge groups (lane bits 3,4,5), fixed deterministic order
    a0 += __shfl_xor(a0, 8, 64);  a1 += __shfl_xor(a1, 8, 64);
    a2 += __shfl_xor(a2, 8, 64);  a3 += __shfl_xor(a3, 8, 64);
    a4 += __shfl_xor(a4, 8, 64);  a5 += __shfl_xor(a5, 8, 64);
    a6 += __shfl_xor(a6, 8, 64);  a7 += __shfl_xor(a7, 8, 64);
    a0 += __shfl_xor(a0, 16, 64); a1 += __shfl_xor(a1, 16, 64);
    a2 += __shfl_xor(a2, 16, 64); a3 += __shfl_xor(a3, 16, 64);
    a4 += __shfl_xor(a4, 16, 64); a5 += __shfl_xor(a5, 16, 64);
    a6 += __shfl_xor(a6, 16, 64); a7 += __shfl_xor(a7, 16, 64);
    a0 += __shfl_xor(a0, 32, 64); a1 += __shfl_xor(a1, 32, 64);
    a2 += __shfl_xor(a2, 32, 64); a3 += __shfl_xor(a3, 32, 64);
    a4 += __shfl_xor(a4, 32, 64); a5 += __shfl_xor(a5, 32, 64);
    a6 += __shfl_xor(a6, 32, 64); a7 += __shfl_xor(a7, 32, 64);

    float f0 = (float)a0, f1 = (float)a1, f2 = (float)a2, f3 = (float)a3;
    float f4 = (float)a4, f5 = (float)a5, f6 = (float)a6, f7 = (float)a7;

    size_t off = (size_t)node * DIM + (d8 << 3);
    const float4 n0 = *reinterpret_cast<const float4*>(nz_layer + off);
    const float4 n1 = *reinterpret_cast<const float4*>(nz_layer + off + 4);
    float ss = n0.x * n0.x + n0.y * n0.y + n0.z * n0.z + n0.w * n0.w
             + n1.x * n1.x + n1.y * n1.y + n1.z * n1.z + n1.w * n1.w;
    // reduce over the 8 dim-chunk lanes (edge groups hold identical copies)
    ss += __shfl_xor(ss, 1, 64);
    ss += __shfl_xor(ss, 2, 64);
    ss += __shfl_xor(ss, 4, 64);
    float e = EPSV / fmaxf(sqrtf(ss), 1e-12f);

    float w0 = f0 + bsign(f0) * n0.x * e;
    float w1 = f1 + bsign(f1) * n0.y * e;
    float w2 = f2 + bsign(f2) * n0.z * e;
    float w3 = f3 + bsign(f3) * n0.w * e;
    float w4 = f4 + bsign(f4) * n1.x * e;
    float w5 = f5 + bsign(f5) * n1.y * e;
    float w6 = f6 + bsign(f6) * n1.z * e;
    float w7 = f7 + bsign(f7) * n1.w * e;

    if (g == 0) {
        if (!is_last) {
            uint4 p;
            p.x = bpack(w0, w1); p.y = bpack(w2, w3);
            p.z = bpack(w4, w5); p.w = bpack(w6, w7);
            *reinterpret_cast<uint4*>(ego_out + ((size_t)node << 5) + (d8 << 2)) = p;
        }
        float4 v0 = make_float4(w0, w1, w2, w3);
        float4 v1 = make_float4(w4, w5, w6, w7);
        if (cl_out) {
            *reinterpret_cast<float4*>(cl_out + off)     = v0;
            *reinterpret_cast<float4*>(cl_out + off + 4) = v1;
        }
        float4 r0, r1;
        if (is_first) {
            r0 = v0; r1 = v1;
        } else {
            const float4 p0 = *reinterpret_cast<const float4*>(acc + off);
            const float4 p1 = *reinterpret_cast<const float4*>(acc + off + 4);
            r0.x = p0.x + v0.x; r0.y = p0.y + v0.y; r0.z = p0.z + v0.z; r0.w = p0.w + v0.w;
            r1.x = p1.x + v1.x; r1.y = p1.y + v1.y; r1.z = p1.z + v1.z; r1.w = p1.w + v1.w;
        }
        if (is_last) {
            const float k = 1.0f / 3.0f;
            r0.x *= k; r0.y *= k; r0.z *= k; r0.w *= k;
            r1.x *= k; r1.y *= k; r1.z *= k; r1.w *= k;
        }
        *reinterpret_cast<float4*>(acc + off)     = r0;
        *reinterpret_cast<float4*>(acc + off + 4) = r1;
    }
}

extern "C" void kernel_launch(void* const* d_in, const int* in_sizes, int n_in,
                              void* d_out, int out_size, void* d_ws, size_t ws_size,
                              hipStream_t stream) {
    const float* user_emb = (const float*)d_in[0];
    const float* item_emb = (const float*)d_in[1];
    const int*   adj_src  = (const int*)d_in[2];
    const int*   adj_dst  = (const int*)d_in[3];
    const float* adj_vals = (const float*)d_in[4];
    const float* noise    = (const float*)d_in[5];
    const int E = in_sizes[2];

    const long long ND = (long long)NN * DIM;
    float* out_final = (float*)d_out;       // [NN, D] final
    float* out_cl    = out_final + ND;      // [NN, D] cl

    // workspace layout (~77.6 MB):
    //  [0, 25.6MB)      ssv_b (pass-A temp), later aliased by egoB0 (bf16 table)
    //  [25.6, 51.2MB)   egoB1 (bf16 ego, layer-1 output)
    //  [51.2, 76.8MB)   ssv (final CSR records)
    //  [76.8MB, ...)    bhist / bbase / boff / row_ptr
    char* w = (char*)d_ws;
    const long long B16 = (long long)NN * (DIM / 2) * 4;   // 25.6 MB
    unsigned int* egoB0 = (unsigned int*)w;                 // aliases ssv_b
    int2*         ssv_b = (int2*)w;
    unsigned int* egoB1 = (unsigned int*)(w + B16);
    int2*         ssv   = (int2*)(w + 2 * B16);
    int*   bhist   = (int*)(w + 3 * B16);                   // NB
    int*   bbase   = bhist + NB;                            // NB + 1
    int*   boff    = bbase + NB + 1;                        // NB
    int*   row_ptr = boff + NB;                             // NN + 1

    const int nchunk = (E + CH - 1) / CH;

    hipMemsetAsync(bhist, 0, NB * sizeof(int), stream);
    bhist_k<<<nchunk, 256, 0, stream>>>(adj_dst, bhist, E);
    bscan_k<<<1, 256, 0, stream>>>(bhist, bbase, boff, row_ptr, E);
    apart_k<<<nchunk, 256, 0, stream>>>(adj_src, adj_dst, adj_vals, boff, ssv_b, E);
    bsort_k<<<NB, 256, 0, stream>>>(bbase, ssv_b, ssv, row_ptr);
    // ssv_b dead -> egoB0 safe to write
    cvt_k<<<(int)(((long long)NN * (DIM / 4) + 255) / 256), 256, 0, stream>>>(
        user_emb, item_emb, egoB0);

    const int spmm_grid = NN / 4;   // 200000 waves, one per dst row
    // layer 1: gather egoB0 -> ego egoB1 (bf16) + cl (f32) ; acc = val
    spmm_fused_k<<<spmm_grid, 256, 0, stream>>>(row_ptr, ssv, egoB0, egoB1,
                                                out_cl, noise, out_final, 1, 0);
    // layer 2: gather egoB1 -> egoB0 (bf16) ; acc += val
    spmm_fused_k<<<spmm_grid, 256, 0, stream>>>(row_ptr, ssv, egoB1, egoB0,
                                                nullptr, noise + ND, out_final, 0, 0);
    // layer 3: gather egoB0 -> (none) ; acc = (acc + val)/3
    spmm_fused_k<<<spmm_grid, 256, 0, stream>>>(row_ptr, ssv, egoB0, nullptr,
                                                nullptr, noise + 2 * ND, out_final, 0, 1);
}

// Round 9
// 745.590 us; speedup vs baseline: 1.3534x; 1.0379x over previous
//
#include <hip/hip_runtime.h>

#define USER_NUM 100000
#define ITEM_NUM 100000
#define NN 200000
#define DIM 64
#define EPSV 0.2f

#define NB 196          // coarse buckets of 1024 dst-nodes (ceil(200000/1024))
#define BSH 10          // bucket = dst >> 10
#define NPB 1024        // nodes per bucket
#define CH 4096         // edges per workgroup chunk in pass A
#define PER 16          // edges per thread (256*16 = 4096)
#define SRC_MASK 0x3FFFF

// ---------------------------------------------------------------------------
// K1: coarse bucket histogram (196 counters) via LDS aggregation
// ---------------------------------------------------------------------------
__global__ __launch_bounds__(256) void bhist_k(const int* __restrict__ dst,
                                               int* __restrict__ bhist, int E) {
    __shared__ int h[NB];
    int t = threadIdx.x;
    for (int i = t; i < NB; i += 256) h[i] = 0;
    __syncthreads();
    long long base = (long long)blockIdx.x * CH;
    #pragma unroll
    for (int j = 0; j < PER; ++j) {
        long long e = base + t + j * 256;
        if (e < E) atomicAdd(&h[dst[e] >> BSH], 1);
    }
    __syncthreads();
    for (int i = t; i < NB; i += 256) if (h[i]) atomicAdd(&bhist[i], h[i]);
}

// ---------------------------------------------------------------------------
// K2: exclusive scan over 196 bucket counts (single block)
// ---------------------------------------------------------------------------
__global__ __launch_bounds__(256) void bscan_k(const int* __restrict__ bhist,
                                               int* __restrict__ bucket_base,
                                               int* __restrict__ bucket_off,
                                               int* __restrict__ row_ptr, int E) {
    __shared__ int tmp[256];
    int t = threadIdx.x;
    int s = (t < NB) ? bhist[t] : 0;
    tmp[t] = s;
    __syncthreads();
    for (int off = 1; off < 256; off <<= 1) {
        int x = (t >= off) ? tmp[t - off] : 0;
        __syncthreads();
        tmp[t] += x;
        __syncthreads();
    }
    int excl = tmp[t] - s;
    if (t < NB) { bucket_base[t] = excl; bucket_off[t] = excl; }
    if (t == 0) { bucket_base[NB] = E; row_ptr[NN] = E; }
}

// ---------------------------------------------------------------------------
// K3 (pass A): LDS multi-split into 196 bucket regions, dense run writes.
// Record: x = src | (dst&1023)<<18 ; y = val bits.
// ---------------------------------------------------------------------------
__global__ __launch_bounds__(256) void apart_k(const int* __restrict__ src,
                                               const int* __restrict__ dst,
                                               const float* __restrict__ vals,
                                               int* __restrict__ bucket_off,
                                               int2* __restrict__ out, int E) {
    __shared__ int cnt[NB], start[NB], cursor[NB], gbase[NB];
    __shared__ int tmp[256];
    __shared__ int2 rec[CH];
    int t = threadIdx.x;
    long long base = (long long)blockIdx.x * CH;
    int nvalid = (int)min((long long)CH, (long long)E - base);

    int s_[PER]; int d_[PER]; float v_[PER];
    for (int i = t; i < NB; i += 256) cnt[i] = 0;
    __syncthreads();
    #pragma unroll
    for (int j = 0; j < PER; ++j) {
        int idx = t + j * 256;
        if (idx < nvalid) {
            long long e = base + idx;
            d_[j] = dst[e]; s_[j] = src[e]; v_[j] = vals[e];
            atomicAdd(&cnt[d_[j] >> BSH], 1);
        } else d_[j] = -1;
    }
    __syncthreads();
    int c = (t < NB) ? cnt[t] : 0;
    tmp[t] = c;
    __syncthreads();
    for (int off = 1; off < 256; off <<= 1) {
        int x = (t >= off) ? tmp[t - off] : 0;
        __syncthreads();
        tmp[t] += x;
        __syncthreads();
    }
    if (t < NB) {
        int excl = tmp[t] - c;
        start[t] = excl; cursor[t] = excl;
        gbase[t] = (c > 0) ? atomicAdd(&bucket_off[t], c) : 0;
    }
    __syncthreads();
    #pragma unroll
    for (int j = 0; j < PER; ++j) {
        if (d_[j] >= 0) {
            int b = d_[j] >> BSH;
            int slot = atomicAdd(&cursor[b], 1);
            rec[slot] = make_int2(s_[j] | ((d_[j] & (NPB - 1)) << 18),
                                  __float_as_int(v_[j]));
        }
    }
    __syncthreads();
    // flush: consecutive LDS slots -> contiguous global runs per bucket
    for (int slot = t; slot < nvalid; slot += 256) {
        int lo = 0, hi = NB - 1;
        while (lo < hi) {
            int mid = (lo + hi + 1) >> 1;
            if (start[mid] <= slot) lo = mid; else hi = mid - 1;
        }
        out[gbase[lo] + (slot - start[lo])] = rec[slot];
    }
}

// ---------------------------------------------------------------------------
// K4 (pass B): one WG per bucket. Per-node hist + scan in LDS -> row_ptr,
// then scatter to final CSR position (random only within ~130KB, 1 CU).
// ---------------------------------------------------------------------------
__global__ __launch_bounds__(256) void bsort_k(const int* __restrict__ bucket_base,
                                               const int2* __restrict__ in,
                                               int2* __restrict__ out,
                                               int* __restrict__ row_ptr) {
    __shared__ int noff[NPB];
    __shared__ int tmp[256];
    int b = blockIdx.x, t = threadIdx.x;
    int rbeg = bucket_base[b], rend = bucket_base[b + 1];
    for (int i = t; i < NPB; i += 256) noff[i] = 0;
    __syncthreads();
    for (int i = rbeg + t; i < rend; i += 256)
        atomicAdd(&noff[(in[i].x >> 18) & (NPB - 1)], 1);
    __syncthreads();
    // exclusive scan of 1024 counters with 256 threads (4 each)
    int l0 = noff[t * 4], l1 = noff[t * 4 + 1], l2 = noff[t * 4 + 2], l3 = noff[t * 4 + 3];
    int s = l0 + l1 + l2 + l3;
    tmp[t] = s;
    __syncthreads();
    for (int off = 1; off < 256; off <<= 1) {
        int x = (t >= off) ? tmp[t - off] : 0;
        __syncthreads();
        tmp[t] += x;
        __syncthreads();
    }
    int run = rbeg + tmp[t] - s;
    int e0 = run, e1 = run + l0, e2 = e1 + l1, e3 = e2 + l2;
    noff[t * 4] = e0; noff[t * 4 + 1] = e1; noff[t * 4 + 2] = e2; noff[t * 4 + 3] = e3;
    int node0 = b * NPB + t * 4;
    if (node0 < NN)     row_ptr[node0]     = e0;
    if (node0 + 1 < NN) row_ptr[node0 + 1] = e1;
    if (node0 + 2 < NN) row_ptr[node0 + 2] = e2;
    if (node0 + 3 < NN) row_ptr[node0 + 3] = e3;
    __syncthreads();
    for (int i = rbeg + t; i < rend; i += 256) {
        int2 r = in[i];
        int pos = atomicAdd(&noff[(r.x >> 18) & (NPB - 1)], 1);
        out[pos] = r;
    }
}

// RNE f32 -> bf16 pack (two floats -> one uint, low half = first)
__device__ __forceinline__ unsigned int bpack(float a, float b) {
    unsigned int ua = __float_as_uint(a), ub = __float_as_uint(b);
    ua = (ua + 0x7fffu + ((ua >> 16) & 1u)) >> 16;
    ub = (ub + 0x7fffu + ((ub >> 16) & 1u)) >> 16;
    return ua | (ub << 16);
}

__device__ __forceinline__ float bsign(float x) {
    return (x > 0.f) ? 1.f : ((x < 0.f) ? -1.f : 0.f);
}

// ---------------------------------------------------------------------------
// K0: convert concat(user_emb, item_emb) f32 -> bf16 table [NN][64]
// (runs after bsort_k; its output aliases the dead pass-A buffer)
// ---------------------------------------------------------------------------
__global__ __launch_bounds__(256) void cvt_k(const float* __restrict__ ue,
                                             const float* __restrict__ ie,
                                             unsigned int* __restrict__ out) {
    long long i = (long long)blockIdx.x * 256 + threadIdx.x;   // float4 index
    const long long tot = (long long)NN * (DIM / 4);           // 3.2M
    if (i >= tot) return;
    const long long uu = (long long)USER_NUM * (DIM / 4);
    const float4 v = (i < uu) ? reinterpret_cast<const float4*>(ue)[i]
                              : reinterpret_cast<const float4*>(ie)[i - uu];
    uint2 p; p.x = bpack(v.x, v.y); p.y = bpack(v.z, v.w);
    reinterpret_cast<uint2*>(out)[i] = p;
}

// unpack a uint4 (8 bf16) and fma into the 8 f64 accumulators
#define FMA8(q, vv)                                                          \
    do {                                                                     \
        float t0 = __uint_as_float((q).x << 16);                             \
        float t1 = __uint_as_float((q).x & 0xffff0000u);                     \
        float t2 = __uint_as_float((q).y << 16);                             \
        float t3 = __uint_as_float((q).y & 0xffff0000u);                     \
        float t4 = __uint_as_float((q).z << 16);                             \
        float t5 = __uint_as_float((q).z & 0xffff0000u);                     \
        float t6 = __uint_as_float((q).w << 16);                             \
        float t7 = __uint_as_float((q).w & 0xffff0000u);                     \
        a0 = fma((double)t0, (vv), a0); a1 = fma((double)t1, (vv), a1);      \
        a2 = fma((double)t2, (vv), a2); a3 = fma((double)t3, (vv), a3);      \
        a4 = fma((double)t4, (vv), a4); a5 = fma((double)t5, (vv), a5);      \
        a6 = fma((double)t6, (vv), a6); a7 = fma((double)t7, (vv), a7);      \
    } while (0)

// ---------------------------------------------------------------------------
// fused segmented SpMM + noise injection + acc (round-5 verified version).
// one 64-lane wave per dst row; 8 edge-groups x 8 lanes; lane gathers
// uint4 = 8 bf16 dims. f64 accumulation for replay-stability (CSR edge order
// varies across graph replays; sign() is discontinuous -- round-1 failure).
// ---------------------------------------------------------------------------
__global__ __launch_bounds__(256) void spmm_fused_k(const int* __restrict__ row_ptr,
                                                    const int2* __restrict__ ssv,
                                                    const unsigned int* __restrict__ ego,
                                                    unsigned int* __restrict__ ego_out,
                                                    float* __restrict__ cl_out,
                                                    const float* __restrict__ nz_layer,
                                                    float* __restrict__ acc,
                                                    int is_first, int is_last) {
    int node = blockIdx.x * 4 + (threadIdx.x >> 6);
    int lane = threadIdx.x & 63;
    int g    = lane >> 3;           // edge slot 0..7 within an 8-edge block
    int d8   = lane & 7;            // which 8-dim chunk of the 64 dims
    int beg = row_ptr[node];
    int end = row_ptr[node + 1];

    double a0 = 0, a1 = 0, a2 = 0, a3 = 0, a4 = 0, a5 = 0, a6 = 0, a7 = 0;
    int base = beg;

    for (; base + 16 <= end; base += 16) {
        int2 svA = ssv[base + g];
        int2 svB = ssv[base + 8 + g];
        int sA = svA.x & SRC_MASK;
        int sB = svB.x & SRC_MASK;
        const uint4 qA = *reinterpret_cast<const uint4*>(ego + ((size_t)sA << 5) + (d8 << 2));
        const uint4 qB = *reinterpret_cast<const uint4*>(ego + ((size_t)sB << 5) + (d8 << 2));
        double vA = (double)__int_as_float(svA.y);
        double vB = (double)__int_as_float(svB.y);
        FMA8(qA, vA);
        FMA8(qB, vB);
    }
    if (base + 8 <= end) {
        int2 sv = ssv[base + g];
        int s = sv.x & SRC_MASK;
        const uint4 q = *reinterpret_cast<const uint4*>(ego + ((size_t)s << 5) + (d8 << 2));
        double v = (double)__int_as_float(sv.y);
        FMA8(q, v);
        base += 8;
    }
    int rem = end - base;
    if (rem > 0) {
        int2 sv = ssv[base + ((g < rem) ? g : 0)];
        int s = sv.x & SRC_MASK;
        const uint4 q = *reinterpret_cast<const uint4*>(ego + ((size_t)s << 5) + (d8 << 2));
        double v = (g < rem) ? (double)__int_as_float(sv.y) : 0.0;
        FMA8(q, v);
    }

    // reduce the 8 edge groups (lane bits 3,4,5), fixed deterministic order
    a0 += __shfl_xor(a0, 8, 64);  a1 += __shfl_xor(a1, 8, 64);
    a2 += __shfl_xor(a2, 8, 64);  a3 += __shfl_xor(a3, 8, 64);
    a4 += __shfl_xor(a4, 8, 64);  a5 += __shfl_xor(a5, 8, 64);
    a6 += __shfl_xor(a6, 8, 64);  a7 += __shfl_xor(a7, 8, 64);
    a0 += __shfl_xor(a0, 16, 64); a1 += __shfl_xor(a1, 16, 64);
    a2 += __shfl_xor(a2, 16, 64); a3 += __shfl_xor(a3, 16, 64);
    a4 += __shfl_xor(a4, 16, 64); a5 += __shfl_xor(a5, 16, 64);
    a6 += __shfl_xor(a6, 16, 64); a7 += __shfl_xor(a7, 16, 64);
    a0 += __shfl_xor(a0, 32, 64); a1 += __shfl_xor(a1, 32, 64);
    a2 += __shfl_xor(a2, 32, 64); a3 += __shfl_xor(a3, 32, 64);
    a4 += __shfl_xor(a4, 32, 64); a5 += __shfl_xor(a5, 32, 64);
    a6 += __shfl_xor(a6, 32, 64); a7 += __shfl_xor(a7, 32, 64);

    float f0 = (float)a0, f1 = (float)a1, f2 = (float)a2, f3 = (float)a3;
    float f4 = (float)a4, f5 = (float)a5, f6 = (float)a6, f7 = (float)a7;

    size_t off = (size_t)node * DIM + (d8 << 3);
    const float4 n0 = *reinterpret_cast<const float4*>(nz_layer + off);
    const float4 n1 = *reinterpret_cast<const float4*>(nz_layer + off + 4);
    float ss = n0.x * n0.x + n0.y * n0.y + n0.z * n0.z + n0.w * n0.w
             + n1.x * n1.x + n1.y * n1.y + n1.z * n1.z + n1.w * n1.w;
    // reduce over the 8 dim-chunk lanes (edge groups hold identical copies)
    ss += __shfl_xor(ss, 1, 64);
    ss += __shfl_xor(ss, 2, 64);
    ss += __shfl_xor(ss, 4, 64);
    float e = EPSV / fmaxf(sqrtf(ss), 1e-12f);

    float w0 = f0 + bsign(f0) * n0.x * e;
    float w1 = f1 + bsign(f1) * n0.y * e;
    float w2 = f2 + bsign(f2) * n0.z * e;
    float w3 = f3 + bsign(f3) * n0.w * e;
    float w4 = f4 + bsign(f4) * n1.x * e;
    float w5 = f5 + bsign(f5) * n1.y * e;
    float w6 = f6 + bsign(f6) * n1.z * e;
    float w7 = f7 + bsign(f7) * n1.w * e;

    if (g == 0) {
        if (!is_last) {
            uint4 p;
            p.x = bpack(w0, w1); p.y = bpack(w2, w3);
            p.z = bpack(w4, w5); p.w = bpack(w6, w7);
            *reinterpret_cast<uint4*>(ego_out + ((size_t)node << 5) + (d8 << 2)) = p;
        }
        float4 v0 = make_float4(w0, w1, w2, w3);
        float4 v1 = make_float4(w4, w5, w6, w7);
        if (cl_out) {
            *reinterpret_cast<float4*>(cl_out + off)     = v0;
            *reinterpret_cast<float4*>(cl_out + off + 4) = v1;
        }
        float4 r0, r1;
        if (is_first) {
            r0 = v0; r1 = v1;
        } else {
            const float4 p0 = *reinterpret_cast<const float4*>(acc + off);
            const float4 p1 = *reinterpret_cast<const float4*>(acc + off + 4);
            r0.x = p0.x + v0.x; r0.y = p0.y + v0.y; r0.z = p0.z + v0.z; r0.w = p0.w + v0.w;
            r1.x = p1.x + v1.x; r1.y = p1.y + v1.y; r1.z = p1.z + v1.z; r1.w = p1.w + v1.w;
        }
        if (is_last) {
            const float k = 1.0f / 3.0f;
            r0.x *= k; r0.y *= k; r0.z *= k; r0.w *= k;
            r1.x *= k; r1.y *= k; r1.z *= k; r1.w *= k;
        }
        *reinterpret_cast<float4*>(acc + off)     = r0;
        *reinterpret_cast<float4*>(acc + off + 4) = r1;
    }
}

extern "C" void kernel_launch(void* const* d_in, const int* in_sizes, int n_in,
                              void* d_out, int out_size, void* d_ws, size_t ws_size,
                              hipStream_t stream) {
    const float* user_emb = (const float*)d_in[0];
    const float* item_emb = (const float*)d_in[1];
    const int*   adj_src  = (const int*)d_in[2];
    const int*   adj_dst  = (const int*)d_in[3];
    const float* adj_vals = (const float*)d_in[4];
    const float* noise    = (const float*)d_in[5];
    const int E = in_sizes[2];

    const long long ND = (long long)NN * DIM;
    float* out_final = (float*)d_out;       // [NN, D] final
    float* out_cl    = out_final + ND;      // [NN, D] cl

    // workspace layout (~77.6 MB):
    //  [0, 25.6MB)      ssv_b (pass-A temp), later aliased by egoB0 (bf16 table)
    //  [25.6, 51.2MB)   egoB1 (bf16 ego, layer-1 output)
    //  [51.2, 76.8MB)   ssv (final CSR records)
    //  [76.8MB, ...)    bhist / bbase / boff / row_ptr
    char* w = (char*)d_ws;
    const long long B16 = (long long)NN * (DIM / 2) * 4;   // 25.6 MB
    unsigned int* egoB0 = (unsigned int*)w;                 // aliases ssv_b
    int2*         ssv_b = (int2*)w;
    unsigned int* egoB1 = (unsigned int*)(w + B16);
    int2*         ssv   = (int2*)(w + 2 * B16);
    int*   bhist   = (int*)(w + 3 * B16);                   // NB
    int*   bbase   = bhist + NB;                            // NB + 1
    int*   boff    = bbase + NB + 1;                        // NB
    int*   row_ptr = boff + NB;                             // NN + 1

    const int nchunk = (E + CH - 1) / CH;

    hipMemsetAsync(bhist, 0, NB * sizeof(int), stream);
    bhist_k<<<nchunk, 256, 0, stream>>>(adj_dst, bhist, E);
    bscan_k<<<1, 256, 0, stream>>>(bhist, bbase, boff, row_ptr, E);
    apart_k<<<nchunk, 256, 0, stream>>>(adj_src, adj_dst, adj_vals, boff, ssv_b, E);
    bsort_k<<<NB, 256, 0, stream>>>(bbase, ssv_b, ssv, row_ptr);
    // ssv_b dead -> egoB0 safe to write
    cvt_k<<<(int)(((long long)NN * (DIM / 4) + 255) / 256), 256, 0, stream>>>(
        user_emb, item_emb, egoB0);

    const int spmm_grid = NN / 4;   // 200000 waves, one per dst row
    // layer 1: gather egoB0 -> ego egoB1 (bf16) + cl (f32) ; acc = val
    spmm_fused_k<<<spmm_grid, 256, 0, stream>>>(row_ptr, ssv, egoB0, egoB1,
                                                out_cl, noise, out_final, 1, 0);
    // layer 2: gather egoB1 -> egoB0 (bf16) ; acc += val
    spmm_fused_k<<<spmm_grid, 256, 0, stream>>>(row_ptr, ssv, egoB1, egoB0,
                                                nullptr, noise + ND, out_final, 0, 0);
    // layer 3: gather egoB0 -> (none) ; acc = (acc + val)/3
    spmm_fused_k<<<spmm_grid, 256, 0, stream>>>(row_ptr, ssv, egoB0, nullptr,
                                                nullptr, noise + 2 * ND, out_final, 0, 1);
}

// Round 11
// 734.462 us; speedup vs baseline: 1.3740x; 1.0152x over previous
//
#include <hip/hip_runtime.h>

#define USER_NUM 100000
#define ITEM_NUM 100000
#define NN 200000
#define DIM 64
#define EPSV 0.2f
#define TINY_TH 1e-3f   // f32 replay jitter ~1e-5 abs; 100x margin

#define NB 196          // coarse buckets of 1024 dst-nodes (ceil(200000/1024))
#define BSH 10          // bucket = dst >> 10
#define NPB 1024        // nodes per bucket
#define CH 4096         // edges per workgroup chunk in pass A
#define PER 16          // edges per thread (256*16 = 4096)
#define SRC_MASK 0x3FFFF

// ---------------------------------------------------------------------------
// K1: coarse bucket histogram (196 counters) via LDS aggregation
// ---------------------------------------------------------------------------
__global__ __launch_bounds__(256) void bhist_k(const int* __restrict__ dst,
                                               int* __restrict__ bhist, int E) {
    __shared__ int h[NB];
    int t = threadIdx.x;
    for (int i = t; i < NB; i += 256) h[i] = 0;
    __syncthreads();
    long long base = (long long)blockIdx.x * CH;
    #pragma unroll
    for (int j = 0; j < PER; ++j) {
        long long e = base + t + j * 256;
        if (e < E) atomicAdd(&h[dst[e] >> BSH], 1);
    }
    __syncthreads();
    for (int i = t; i < NB; i += 256) if (h[i]) atomicAdd(&bhist[i], h[i]);
}

// ---------------------------------------------------------------------------
// K2: exclusive scan over 196 bucket counts (single block)
// ---------------------------------------------------------------------------
__global__ __launch_bounds__(256) void bscan_k(const int* __restrict__ bhist,
                                               int* __restrict__ bucket_base,
                                               int* __restrict__ bucket_off,
                                               int* __restrict__ row_ptr, int E) {
    __shared__ int tmp[256];
    int t = threadIdx.x;
    int s = (t < NB) ? bhist[t] : 0;
    tmp[t] = s;
    __syncthreads();
    for (int off = 1; off < 256; off <<= 1) {
        int x = (t >= off) ? tmp[t - off] : 0;
        __syncthreads();
        tmp[t] += x;
        __syncthreads();
    }
    int excl = tmp[t] - s;
    if (t < NB) { bucket_base[t] = excl; bucket_off[t] = excl; }
    if (t == 0) { bucket_base[NB] = E; row_ptr[NN] = E; }
}

// ---------------------------------------------------------------------------
// K3 (pass A): LDS multi-split into 196 bucket regions, dense run writes.
// Record: x = src | (dst&1023)<<18 ; y = val bits.
// ---------------------------------------------------------------------------
__global__ __launch_bounds__(256) void apart_k(const int* __restrict__ src,
                                               const int* __restrict__ dst,
                                               const float* __restrict__ vals,
                                               int* __restrict__ bucket_off,
                                               int2* __restrict__ out, int E) {
    __shared__ int cnt[NB], start[NB], cursor[NB], gbase[NB];
    __shared__ int tmp[256];
    __shared__ int2 rec[CH];
    int t = threadIdx.x;
    long long base = (long long)blockIdx.x * CH;
    int nvalid = (int)min((long long)CH, (long long)E - base);

    int s_[PER]; int d_[PER]; float v_[PER];
    for (int i = t; i < NB; i += 256) cnt[i] = 0;
    __syncthreads();
    #pragma unroll
    for (int j = 0; j < PER; ++j) {
        int idx = t + j * 256;
        if (idx < nvalid) {
            long long e = base + idx;
            d_[j] = dst[e]; s_[j] = src[e]; v_[j] = vals[e];
            atomicAdd(&cnt[d_[j] >> BSH], 1);
        } else d_[j] = -1;
    }
    __syncthreads();
    int c = (t < NB) ? cnt[t] : 0;
    tmp[t] = c;
    __syncthreads();
    for (int off = 1; off < 256; off <<= 1) {
        int x = (t >= off) ? tmp[t - off] : 0;
        __syncthreads();
        tmp[t] += x;
        __syncthreads();
    }
    if (t < NB) {
        int excl = tmp[t] - c;
        start[t] = excl; cursor[t] = excl;
        gbase[t] = (c > 0) ? atomicAdd(&bucket_off[t], c) : 0;
    }
    __syncthreads();
    #pragma unroll
    for (int j = 0; j < PER; ++j) {
        if (d_[j] >= 0) {
            int b = d_[j] >> BSH;
            int slot = atomicAdd(&cursor[b], 1);
            rec[slot] = make_int2(s_[j] | ((d_[j] & (NPB - 1)) << 18),
                                  __float_as_int(v_[j]));
        }
    }
    __syncthreads();
    // flush: consecutive LDS slots -> contiguous global runs per bucket
    for (int slot = t; slot < nvalid; slot += 256) {
        int lo = 0, hi = NB - 1;
        while (lo < hi) {
            int mid = (lo + hi + 1) >> 1;
            if (start[mid] <= slot) lo = mid; else hi = mid - 1;
        }
        out[gbase[lo] + (slot - start[lo])] = rec[slot];
    }
}

// ---------------------------------------------------------------------------
// K4 (pass B): one WG per bucket. Per-node hist + scan in LDS -> row_ptr,
// then scatter to final CSR position (random only within ~130KB, 1 CU).
// ---------------------------------------------------------------------------
__global__ __launch_bounds__(256) void bsort_k(const int* __restrict__ bucket_base,
                                               const int2* __restrict__ in,
                                               int2* __restrict__ out,
                                               int* __restrict__ row_ptr) {
    __shared__ int noff[NPB];
    __shared__ int tmp[256];
    int b = blockIdx.x, t = threadIdx.x;
    int rbeg = bucket_base[b], rend = bucket_base[b + 1];
    for (int i = t; i < NPB; i += 256) noff[i] = 0;
    __syncthreads();
    for (int i = rbeg + t; i < rend; i += 256)
        atomicAdd(&noff[(in[i].x >> 18) & (NPB - 1)], 1);
    __syncthreads();
    // exclusive scan of 1024 counters with 256 threads (4 each)
    int l0 = noff[t * 4], l1 = noff[t * 4 + 1], l2 = noff[t * 4 + 2], l3 = noff[t * 4 + 3];
    int s = l0 + l1 + l2 + l3;
    tmp[t] = s;
    __syncthreads();
    for (int off = 1; off < 256; off <<= 1) {
        int x = (t >= off) ? tmp[t - off] : 0;
        __syncthreads();
        tmp[t] += x;
        __syncthreads();
    }
    int run = rbeg + tmp[t] - s;
    int e0 = run, e1 = run + l0, e2 = e1 + l1, e3 = e2 + l2;
    noff[t * 4] = e0; noff[t * 4 + 1] = e1; noff[t * 4 + 2] = e2; noff[t * 4 + 3] = e3;
    int node0 = b * NPB + t * 4;
    if (node0 < NN)     row_ptr[node0]     = e0;
    if (node0 + 1 < NN) row_ptr[node0 + 1] = e1;
    if (node0 + 2 < NN) row_ptr[node0 + 2] = e2;
    if (node0 + 3 < NN) row_ptr[node0 + 3] = e3;
    __syncthreads();
    for (int i = rbeg + t; i < rend; i += 256) {
        int2 r = in[i];
        int pos = atomicAdd(&noff[(r.x >> 18) & (NPB - 1)], 1);
        out[pos] = r;
    }
}

// RNE f32 -> bf16 pack (two floats -> one uint, low half = first)
__device__ __forceinline__ unsigned int bpack(float a, float b) {
    unsigned int ua = __float_as_uint(a), ub = __float_as_uint(b);
    ua = (ua + 0x7fffu + ((ua >> 16) & 1u)) >> 16;
    ub = (ub + 0x7fffu + ((ub >> 16) & 1u)) >> 16;
    return ua | (ub << 16);
}

__device__ __forceinline__ float bsign(float x) {
    return (x > 0.f) ? 1.f : ((x < 0.f) ? -1.f : 0.f);
}

// ---------------------------------------------------------------------------
// K0: convert concat(user_emb, item_emb) f32 -> bf16 table [NN][64]
// (runs after bsort_k; its output aliases the dead pass-A buffer)
// ---------------------------------------------------------------------------
__global__ __launch_bounds__(256) void cvt_k(const float* __restrict__ ue,
                                             const float* __restrict__ ie,
                                             unsigned int* __restrict__ out) {
    long long i = (long long)blockIdx.x * 256 + threadIdx.x;   // float4 index
    const long long tot = (long long)NN * (DIM / 4);           // 3.2M
    if (i >= tot) return;
    const long long uu = (long long)USER_NUM * (DIM / 4);
    const float4 v = (i < uu) ? reinterpret_cast<const float4*>(ue)[i]
                              : reinterpret_cast<const float4*>(ie)[i - uu];
    uint2 p; p.x = bpack(v.x, v.y); p.y = bpack(v.z, v.w);
    reinterpret_cast<uint2*>(out)[i] = p;
}

// unpack a uint4 (8 bf16) and fma into 8 f32 accumulators (fast path)
#define FMA8F(q, vv)                                                         \
    do {                                                                     \
        b0 = fmaf(__uint_as_float((q).x << 16),          (vv), b0);          \
        b1 = fmaf(__uint_as_float((q).x & 0xffff0000u),  (vv), b1);          \
        b2 = fmaf(__uint_as_float((q).y << 16),          (vv), b2);          \
        b3 = fmaf(__uint_as_float((q).y & 0xffff0000u),  (vv), b3);          \
        b4 = fmaf(__uint_as_float((q).z << 16),          (vv), b4);          \
        b5 = fmaf(__uint_as_float((q).z & 0xffff0000u),  (vv), b5);          \
        b6 = fmaf(__uint_as_float((q).w << 16),          (vv), b6);          \
        b7 = fmaf(__uint_as_float((q).w & 0xffff0000u),  (vv), b7);          \
    } while (0)

// unpack a uint4 (8 bf16) and fma into 8 f64 accumulators (rescue path)
#define FMA8D(q, vv)                                                         \
    do {                                                                     \
        a0 = fma((double)__uint_as_float((q).x << 16),         (vv), a0);    \
        a1 = fma((double)__uint_as_float((q).x & 0xffff0000u), (vv), a1);    \
        a2 = fma((double)__uint_as_float((q).y << 16),         (vv), a2);    \
        a3 = fma((double)__uint_as_float((q).y & 0xffff0000u), (vv), a3);    \
        a4 = fma((double)__uint_as_float((q).z << 16),         (vv), a4);    \
        a5 = fma((double)__uint_as_float((q).z & 0xffff0000u), (vv), a5);    \
        a6 = fma((double)__uint_as_float((q).w << 16),         (vv), a6);    \
        a7 = fma((double)__uint_as_float((q).w & 0xffff0000u), (vv), a7);    \
    } while (0)

// ---------------------------------------------------------------------------
// fused segmented SpMM + noise injection + acc.
// one 64-lane wave per dst row; 8 edge-groups x 8 lanes; lane gathers
// uint4 = 8 bf16 dims.
// REPLAY-STABILITY (round-1 lesson: CSR edge order varies across graph
// replays, sign() is discontinuous): f32 fast path, and iff any of the row's
// 64 sums has |a| < TINY_TH (f32 replay jitter ~1e-5 << 1e-3), the wave
// re-runs the row with f64 accumulation (~2% of rows). For |a| >= TINY_TH
// the f32 sign is replay-stable by margin; near the threshold both paths
// agree on sign, so branch jitter is harmless.
// ---------------------------------------------------------------------------
__global__ __launch_bounds__(256) void spmm_fused_k(const int* __restrict__ row_ptr,
                                                    const int2* __restrict__ ssv,
                                                    const unsigned int* __restrict__ ego,
                                                    unsigned int* __restrict__ ego_out,
                                                    float* __restrict__ cl_out,
                                                    const float* __restrict__ nz_layer,
                                                    float* __restrict__ acc,
                                                    int is_first, int is_last) {
    int node = blockIdx.x * 4 + (threadIdx.x >> 6);
    int lane = threadIdx.x & 63;
    int g    = lane >> 3;           // edge slot 0..7 within an 8-edge block
    int d8   = lane & 7;            // which 8-dim chunk of the 64 dims
    int beg = row_ptr[node];
    int end = row_ptr[node + 1];

    float b0 = 0.f, b1 = 0.f, b2 = 0.f, b3 = 0.f,
          b4 = 0.f, b5 = 0.f, b6 = 0.f, b7 = 0.f;
    int base = beg;

    for (; base + 16 <= end; base += 16) {
        int2 svA = ssv[base + g];
        int2 svB = ssv[base + 8 + g];
        int sA = svA.x & SRC_MASK;
        int sB = svB.x & SRC_MASK;
        const uint4 qA = *reinterpret_cast<const uint4*>(ego + ((size_t)sA << 5) + (d8 << 2));
        const uint4 qB = *reinterpret_cast<const uint4*>(ego + ((size_t)sB << 5) + (d8 << 2));
        float vA = __int_as_float(svA.y);
        float vB = __int_as_float(svB.y);
        FMA8F(qA, vA);
        FMA8F(qB, vB);
    }
    if (base + 8 <= end) {
        int2 sv = ssv[base + g];
        int s = sv.x & SRC_MASK;
        const uint4 q = *reinterpret_cast<const uint4*>(ego + ((size_t)s << 5) + (d8 << 2));
        float v = __int_as_float(sv.y);
        FMA8F(q, v);
        base += 8;
    }
    {
        int rem = end - base;
        if (rem > 0) {
            int2 sv = ssv[base + ((g < rem) ? g : 0)];
            int s = sv.x & SRC_MASK;
            const uint4 q = *reinterpret_cast<const uint4*>(ego + ((size_t)s << 5) + (d8 << 2));
            float v = (g < rem) ? __int_as_float(sv.y) : 0.0f;
            FMA8F(q, v);
        }
    }

    // reduce the 8 edge groups (lane bits 3,4,5); all lanes end with totals
    b0 += __shfl_xor(b0, 8, 64);  b1 += __shfl_xor(b1, 8, 64);
    b2 += __shfl_xor(b2, 8, 64);  b3 += __shfl_xor(b3, 8, 64);
    b4 += __shfl_xor(b4, 8, 64);  b5 += __shfl_xor(b5, 8, 64);
    b6 += __shfl_xor(b6, 8, 64);  b7 += __shfl_xor(b7, 8, 64);
    b0 += __shfl_xor(b0, 16, 64); b1 += __shfl_xor(b1, 16, 64);
    b2 += __shfl_xor(b2, 16, 64); b3 += __shfl_xor(b3, 16, 64);
    b4 += __shfl_xor(b4, 16, 64); b5 += __shfl_xor(b5, 16, 64);
    b6 += __shfl_xor(b6, 16, 64); b7 += __shfl_xor(b7, 16, 64);
    b0 += __shfl_xor(b0, 32, 64); b1 += __shfl_xor(b1, 32, 64);
    b2 += __shfl_xor(b2, 32, 64); b3 += __shfl_xor(b3, 32, 64);
    b4 += __shfl_xor(b4, 32, 64); b5 += __shfl_xor(b5, 32, 64);
    b6 += __shfl_xor(b6, 32, 64); b7 += __shfl_xor(b7, 32, 64);

    float f0 = b0, f1 = b1, f2 = b2, f3 = b3;
    float f4 = b4, f5 = b5, f6 = b6, f7 = b7;

    // rare rescue: any near-zero sum in this row -> redo row in f64
    float mn01 = fminf(fminf(fabsf(f0), fabsf(f1)), fminf(fabsf(f2), fabsf(f3)));
    float mn23 = fminf(fminf(fabsf(f4), fabsf(f5)), fminf(fabsf(f6), fabsf(f7)));
    if (__builtin_expect(__any(fminf(mn01, mn23) < TINY_TH), 0)) {
        double a0 = 0, a1 = 0, a2 = 0, a3 = 0, a4 = 0, a5 = 0, a6 = 0, a7 = 0;
        int bb = beg;
        for (; bb + 8 <= end; bb += 8) {
            int2 sv = ssv[bb + g];
            int s = sv.x & SRC_MASK;
            const uint4 q = *reinterpret_cast<const uint4*>(ego + ((size_t)s << 5) + (d8 << 2));
            double v = (double)__int_as_float(sv.y);
            FMA8D(q, v);
        }
        int rem = end - bb;
        if (rem > 0) {
            int2 sv = ssv[bb + ((g < rem) ? g : 0)];
            int s = sv.x & SRC_MASK;
            const uint4 q = *reinterpret_cast<const uint4*>(ego + ((size_t)s << 5) + (d8 << 2));
            double v = (g < rem) ? (double)__int_as_float(sv.y) : 0.0;
            FMA8D(q, v);
        }
        a0 += __shfl_xor(a0, 8, 64);  a1 += __shfl_xor(a1, 8, 64);
        a2 += __shfl_xor(a2, 8, 64);  a3 += __shfl_xor(a3, 8, 64);
        a4 += __shfl_xor(a4, 8, 64);  a5 += __shfl_xor(a5, 8, 64);
        a6 += __shfl_xor(a6, 8, 64);  a7 += __shfl_xor(a7, 8, 64);
        a0 += __shfl_xor(a0, 16, 64); a1 += __shfl_xor(a1, 16, 64);
        a2 += __shfl_xor(a2, 16, 64); a3 += __shfl_xor(a3, 16, 64);
        a4 += __shfl_xor(a4, 16, 64); a5 += __shfl_xor(a5, 16, 64);
        a6 += __shfl_xor(a6, 16, 64); a7 += __shfl_xor(a7, 16, 64);
        a0 += __shfl_xor(a0, 32, 64); a1 += __shfl_xor(a1, 32, 64);
        a2 += __shfl_xor(a2, 32, 64); a3 += __shfl_xor(a3, 32, 64);
        a4 += __shfl_xor(a4, 32, 64); a5 += __shfl_xor(a5, 32, 64);
        a6 += __shfl_xor(a6, 32, 64); a7 += __shfl_xor(a7, 32, 64);
        f0 = (float)a0; f1 = (float)a1; f2 = (float)a2; f3 = (float)a3;
        f4 = (float)a4; f5 = (float)a5; f6 = (float)a6; f7 = (float)a7;
    }

    size_t off = (size_t)node * DIM + (d8 << 3);
    const float4 n0 = *reinterpret_cast<const float4*>(nz_layer + off);
    const float4 n1 = *reinterpret_cast<const float4*>(nz_layer + off + 4);
    float ss = n0.x * n0.x + n0.y * n0.y + n0.z * n0.z + n0.w * n0.w
             + n1.x * n1.x + n1.y * n1.y + n1.z * n1.z + n1.w * n1.w;
    // reduce over the 8 dim-chunk lanes (edge groups hold identical copies)
    ss += __shfl_xor(ss, 1, 64);
    ss += __shfl_xor(ss, 2, 64);
    ss += __shfl_xor(ss, 4, 64);
    float e = EPSV / fmaxf(sqrtf(ss), 1e-12f);

    float w0 = f0 + bsign(f0) * n0.x * e;
    float w1 = f1 + bsign(f1) * n0.y * e;
    float w2 = f2 + bsign(f2) * n0.z * e;
    float w3 = f3 + bsign(f3) * n0.w * e;
    float w4 = f4 + bsign(f4) * n1.x * e;
    float w5 = f5 + bsign(f5) * n1.y * e;
    float w6 = f6 + bsign(f6) * n1.z * e;
    float w7 = f7 + bsign(f7) * n1.w * e;

    if (g == 0) {
        if (!is_last) {
            uint4 p;
            p.x = bpack(w0, w1); p.y = bpack(w2, w3);
            p.z = bpack(w4, w5); p.w = bpack(w6, w7);
            *reinterpret_cast<uint4*>(ego_out + ((size_t)node << 5) + (d8 << 2)) = p;
        }
        float4 v0 = make_float4(w0, w1, w2, w3);
        float4 v1 = make_float4(w4, w5, w6, w7);
        if (cl_out) {
            *reinterpret_cast<float4*>(cl_out + off)     = v0;
            *reinterpret_cast<float4*>(cl_out + off + 4) = v1;
        }
        float4 r0, r1;
        if (is_first) {
            r0 = v0; r1 = v1;
        } else {
            const float4 p0 = *reinterpret_cast<const float4*>(acc + off);
            const float4 p1 = *reinterpret_cast<const float4*>(acc + off + 4);
            r0.x = p0.x + v0.x; r0.y = p0.y + v0.y; r0.z = p0.z + v0.z; r0.w = p0.w + v0.w;
            r1.x = p1.x + v1.x; r1.y = p1.y + v1.y; r1.z = p1.z + v1.z; r1.w = p1.w + v1.w;
        }
        if (is_last) {
            const float k = 1.0f / 3.0f;
            r0.x *= k; r0.y *= k; r0.z *= k; r0.w *= k;
            r1.x *= k; r1.y *= k; r1.z *= k; r1.w *= k;
        }
        *reinterpret_cast<float4*>(acc + off)     = r0;
        *reinterpret_cast<float4*>(acc + off + 4) = r1;
    }
}

extern "C" void kernel_launch(void* const* d_in, const int* in_sizes, int n_in,
                              void* d_out, int out_size, void* d_ws, size_t ws_size,
                              hipStream_t stream) {
    const float* user_emb = (const float*)d_in[0];
    const float* item_emb = (const float*)d_in[1];
    const int*   adj_src  = (const int*)d_in[2];
    const int*   adj_dst  = (const int*)d_in[3];
    const float* adj_vals = (const float*)d_in[4];
    const float* noise    = (const float*)d_in[5];
    const int E = in_sizes[2];

    const long long ND = (long long)NN * DIM;
    float* out_final = (float*)d_out;       // [NN, D] final
    float* out_cl    = out_final + ND;      // [NN, D] cl

    // workspace layout (~77.6 MB):
    //  [0, 25.6MB)      ssv_b (pass-A temp), later aliased by egoB0 (bf16 table)
    //  [25.6, 51.2MB)   egoB1 (bf16 ego, layer-1 output)
    //  [51.2, 76.8MB)   ssv (final CSR records)
    //  [76.8MB, ...)    bhist / bbase / boff / row_ptr
    char* w = (char*)d_ws;
    const long long B16 = (long long)NN * (DIM / 2) * 4;   // 25.6 MB
    unsigned int* egoB0 = (unsigned int*)w;                 // aliases ssv_b
    int2*         ssv_b = (int2*)w;
    unsigned int* egoB1 = (unsigned int*)(w + B16);
    int2*         ssv   = (int2*)(w + 2 * B16);
    int*   bhist   = (int*)(w + 3 * B16);                   // NB
    int*   bbase   = bhist + NB;                            // NB + 1
    int*   boff    = bbase + NB + 1;                        // NB
    int*   row_ptr = boff + NB;                             // NN + 1

    const int nchunk = (E + CH - 1) / CH;

    hipMemsetAsync(bhist, 0, NB * sizeof(int), stream);
    bhist_k<<<nchunk, 256, 0, stream>>>(adj_dst, bhist, E);
    bscan_k<<<1, 256, 0, stream>>>(bhist, bbase, boff, row_ptr, E);
    apart_k<<<nchunk, 256, 0, stream>>>(adj_src, adj_dst, adj_vals, boff, ssv_b, E);
    bsort_k<<<NB, 256, 0, stream>>>(bbase, ssv_b, ssv, row_ptr);
    // ssv_b dead -> egoB0 safe to write
    cvt_k<<<(int)(((long long)NN * (DIM / 4) + 255) / 256), 256, 0, stream>>>(
        user_emb, item_emb, egoB0);

    const int spmm_grid = NN / 4;   // 200000 waves, one per dst row
    // layer 1: gather egoB0 -> ego egoB1 (bf16) + cl (f32) ; acc = val
    spmm_fused_k<<<spmm_grid, 256, 0, stream>>>(row_ptr, ssv, egoB0, egoB1,
                                                out_cl, noise, out_final, 1, 0);
    // layer 2: gather egoB1 -> egoB0 (bf16) ; acc += val
    spmm_fused_k<<<spmm_grid, 256, 0, stream>>>(row_ptr, ssv, egoB1, egoB0,
                                                nullptr, noise + ND, out_final, 0, 0);
    // layer 3: gather egoB0 -> (none) ; acc = (acc + val)/3
    spmm_fused_k<<<spmm_grid, 256, 0, stream>>>(row_ptr, ssv, egoB0, nullptr,
                                                nullptr, noise + 2 * ND, out_final, 0, 1);
}